// Round 5
// baseline (468.025 us; speedup 1.0000x reference)
//
#include <hip/hip_runtime.h>

namespace {

constexpr int S    = 384;
constexpr int D    = 64;
constexpr int QT   = 16;        // q-rows per block (small => 5 blocks/CU)
constexpr int KC   = 64;        // V k-chunk per stage
constexpr int NCH  = S / KC;    // 6
constexpr int PROW = 384;       // shorts per P_lds row (48 x 16B groups)
constexpr int VROW = 64;        // shorts per Vt row per buffer (8 x 16B groups)

typedef float        f32x4  __attribute__((ext_vector_type(4)));
typedef unsigned int u32x2  __attribute__((ext_vector_type(2)));
typedef unsigned int u32x4  __attribute__((ext_vector_type(4)));
typedef __bf16       bf16x8 __attribute__((ext_vector_type(8)));

__device__ __forceinline__ unsigned int f2bf(float f) {
    // round-to-nearest-even fp32 -> bf16 (finite inputs)
    unsigned int u = __float_as_uint(f);
    u += 0x7fffu + ((u >> 16) & 1u);
    return u >> 16;
}

__global__ __launch_bounds__(256, 5)
void softmax_drop_pv(const float* __restrict__ scores,
                     const float* __restrict__ vmat,
                     const float* __restrict__ dmask,
                     float* __restrict__ out)
{
    // 12288 + 16384 + 64 = 28736 B -> 5 blocks/CU -> 20 waves/CU
    __shared__ alignas(16) unsigned short P_lds[QT * PROW];
    __shared__ alignas(16) unsigned short Vt_lds[2][D * VROW];
    __shared__ float linv[QT];

    const int tid  = threadIdx.x;
    const int lane = tid & 63;
    const int wave = tid >> 6;    // 0..3
    const int rh   = lane >> 5;   // half-wave id: which row of the pair
    const int l32  = lane & 31;
    const int bh   = blockIdx.x / (S / QT);
    const int q0   = (blockIdx.x % (S / QT)) * QT;
    const size_t rb0 = ((size_t)bh * S + q0) * S;

    unsigned int* P32 = reinterpret_cast<unsigned int*>(P_lds);

    // ------------- Phase 0: softmax*mask -> bf16 P (unnormalized) -----------
    // Each wave owns 4 q-rows; half-wave owns one row per iteration (2 iters).
    // PLAIN loads this round (nt-hint experiment): let L2/LLC serve the
    // freshly-restored inputs at full rate.
    f32x4 sv[2][3], mv[2][3];
    auto issue = [&](int i, int sl) {
        const int row = wave * 4 + 2 * i + rh;
        const f32x4* sp =
            reinterpret_cast<const f32x4*>(scores + rb0 + (size_t)row * S) + l32;
        const f32x4* mp =
            reinterpret_cast<const f32x4*>(dmask  + rb0 + (size_t)row * S) + l32;
        sv[sl][0] = sp[0];
        sv[sl][1] = sp[32];
        sv[sl][2] = sp[64];
        mv[sl][0] = mp[0];
        mv[sl][1] = mp[32];
        mv[sl][2] = mp[64];
    };

    issue(0, 0);
#pragma unroll
    for (int i = 0; i < 2; ++i) {
        const int cur = i & 1;
        if (i < 1) issue(i + 1, cur ^ 1);   // prefetch next row pair

        const int row = wave * 4 + 2 * i + rh;
        const f32x4 s0 = sv[cur][0], s1 = sv[cur][1], s2 = sv[cur][2];
        const f32x4 m0 = mv[cur][0], m1 = mv[cur][1], m2 = mv[cur][2];

        float mx = fmaxf(fmaxf(fmaxf(s0.x, s0.y), fmaxf(s0.z, s0.w)),
                   fmaxf(fmaxf(fmaxf(s1.x, s1.y), fmaxf(s1.z, s1.w)),
                         fmaxf(fmaxf(s2.x, s2.y), fmaxf(s2.z, s2.w))));
#pragma unroll
        for (int d = 16; d >= 1; d >>= 1)   // stays within 32-lane half
            mx = fmaxf(mx, __shfl_xor(mx, d, 64));

        const float e0  = __expf(s0.x - mx), e1  = __expf(s0.y - mx);
        const float e2  = __expf(s0.z - mx), e3  = __expf(s0.w - mx);
        const float e4  = __expf(s1.x - mx), e5  = __expf(s1.y - mx);
        const float e6  = __expf(s1.z - mx), e7  = __expf(s1.w - mx);
        const float e8  = __expf(s2.x - mx), e9  = __expf(s2.y - mx);
        const float e10 = __expf(s2.z - mx), e11 = __expf(s2.w - mx);

        float l = (((e0 + e1) + (e2 + e3)) + ((e4 + e5) + (e6 + e7))) +
                  ((e8 + e9) + (e10 + e11));
#pragma unroll
        for (int d = 16; d >= 1; d >>= 1)
            l += __shfl_xor(l, d, 64);
        if (l32 == 0) linv[row] = 1.0f / l;   // normalization deferred

        u32x2 w0, w1, w2;   // p = exp * mask, packed bf16 (unnormalized)
        w0.x = f2bf(e0  * m0.x) | (f2bf(e1  * m0.y) << 16);
        w0.y = f2bf(e2  * m0.z) | (f2bf(e3  * m0.w) << 16);
        w1.x = f2bf(e4  * m1.x) | (f2bf(e5  * m1.y) << 16);
        w1.y = f2bf(e6  * m1.z) | (f2bf(e7  * m1.w) << 16);
        w2.x = f2bf(e8  * m2.x) | (f2bf(e9  * m2.y) << 16);
        w2.y = f2bf(e10 * m2.z) | (f2bf(e11 * m2.w) << 16);

        // 16B k-group g = j*16 + (l32>>1); octet-XOR swizzle by (row&7)
        const int xsw = row & 7;
        const int gb  = l32 >> 1;
        unsigned int* prow =
            P32 + row * (PROW / 2) + ((gb ^ xsw) << 2) + ((l32 & 1) << 1);
        *reinterpret_cast<u32x2*>(prow)       = w0;
        *reinterpret_cast<u32x2*>(prow + 64)  = w1;
        *reinterpret_cast<u32x2*>(prow + 128) = w2;
    }

    // ------------- Phase 1: P @ V via bf16 MFMA, dbuf V staging -------------
    // 4 waves: each stages 2 k-groups/chunk; all waves share the 16-row
    // A-fragment (read-only); wave w owns output d-quarter w*16.
    auto stage = [&](int ch, int buf) {
#pragma unroll
        for (int ii = 0; ii < 2; ++ii) {
            const int kg = ii * 4 + wave;   // chunk-local k-group (8 k's)
            const float* vp =
                vmat + ((size_t)bh * S + ch * KC + kg * 8) * D + lane;
            const float v0 = vp[0 * D], v1 = vp[1 * D];
            const float v2 = vp[2 * D], v3 = vp[3 * D];
            const float v4 = vp[4 * D], v5 = vp[5 * D];
            const float v6 = vp[6 * D], v7 = vp[7 * D];
            u32x4 pk;
            pk.x = f2bf(v0) | (f2bf(v1) << 16);
            pk.y = f2bf(v2) | (f2bf(v3) << 16);
            pk.z = f2bf(v4) | (f2bf(v5) << 16);
            pk.w = f2bf(v6) | (f2bf(v7) << 16);
            *reinterpret_cast<u32x4*>(
                &Vt_lds[buf][lane * VROW + ((kg ^ (lane & 7)) << 3)]) = pk;
        }
    };

    f32x4 acc = {};
    const int quad  = lane >> 4;
    const int qrow  = lane & 15;          // shared 16-row A tile
    const int qx    = qrow & 7;
    const int dbase = lane & 15;

    stage(0, 0);
    __syncthreads();   // covers phase-0 P writes, linv, and chunk-0 V stage

#pragma unroll
    for (int ch = 0; ch < NCH; ++ch) {
        if (ch < NCH - 1) stage(ch + 1, (ch + 1) & 1);   // overlap with MFMA
#pragma unroll
        for (int s = 0; s < 2; ++s) {
            const int kgG = ch * 8 + s * 4 + quad;       // global P k-group
            const bf16x8 a = *reinterpret_cast<const bf16x8*>(
                &P_lds[qrow * PROW + ((kgG ^ qx) << 3)]);
            const int kgl = s * 4 + quad;                // chunk-local group
            const int dcol = wave * 16 + dbase;
            const bf16x8 b = *reinterpret_cast<const bf16x8*>(
                &Vt_lds[ch & 1][dcol * VROW + ((kgl ^ (dcol & 7)) << 3)]);
            acc = __builtin_amdgcn_mfma_f32_16x16x32_bf16(a, b, acc, 0, 0, 0);
        }
        if (ch < NCH - 1) __syncthreads();
    }

    // ------------- Epilogue: scale by 1/l, store fp32 -----------------------
    // C/D layout (m89-verified): col = lane&15, row = (lane>>4)*4 + reg
    const size_t ob   = ((size_t)bh * S + q0) * D;
    const int    orow = quad << 2;
    const int    ocol = wave * 16 + dbase;
    float iv[4];
#pragma unroll
    for (int r = 0; r < 4; ++r) iv[r] = linv[orow + r];
#pragma unroll
    for (int r = 0; r < 4; ++r) {
        out[ob + (size_t)(orow + r) * D + ocol] = acc[r] * iv[r];
    }
}

} // namespace

extern "C" void kernel_launch(void* const* d_in, const int* in_sizes, int n_in,
                              void* d_out, int out_size, void* d_ws, size_t ws_size,
                              hipStream_t stream)
{
    const float* scores = (const float*)d_in[0];  // x429 [B,H,S,S]
    const float* vmat   = (const float*)d_in[1];  // x419 [B,H,S,D]
    const float* dmask  = (const float*)d_in[2];  // dropout_mask [B,H,S,S]
    float* out = (float*)d_out;                   // [B,H,S,D] fp32

    const int BH = 32 * 12;
    dim3 grid(BH * (S / QT));   // 9216 blocks
    dim3 block(256);
    softmax_drop_pv<<<grid, block, 0, stream>>>(scores, vmat, dmask, out);
}

// Round 6
// 451.686 us; speedup vs baseline: 1.0362x; 1.0362x over previous
//
#include <hip/hip_runtime.h>

namespace {

constexpr int S    = 384;
constexpr int D    = 64;
constexpr int QT   = 16;        // q-rows per tile
constexpr int TPB  = 6;         // tiles per block; 24 tiles/bh -> 4 blocks/bh
constexpr int PROW = 384;       // shorts per P_lds row (48 x 16B k-groups)
constexpr int VROW = 384;       // shorts per V_lds row (full K, 48 groups)

typedef float        f32x4  __attribute__((ext_vector_type(4)));
typedef unsigned int u32x2  __attribute__((ext_vector_type(2)));
typedef unsigned int u32x4  __attribute__((ext_vector_type(4)));
typedef __bf16       bf16x8 __attribute__((ext_vector_type(8)));

__device__ __forceinline__ unsigned int f2bf(float f) {
    // round-to-nearest-even fp32 -> bf16 (finite inputs)
    unsigned int u = __float_as_uint(f);
    u += 0x7fffu + ((u >> 16) & 1u);
    return u >> 16;
}

__global__ __launch_bounds__(256, 2)
void softmax_drop_pv(const float* __restrict__ scores,
                     const float* __restrict__ vmat,
                     const float* __restrict__ dmask,
                     float* __restrict__ out)
{
    // 12288 (P) + 49152 (V full) + 64 = 61.5 KB -> 2 blocks/CU
    __shared__ alignas(16) unsigned short P_lds[QT * PROW];
    __shared__ alignas(16) unsigned short V_lds[D * VROW];
    __shared__ float linv[QT];

    const int tid  = threadIdx.x;
    const int lane = tid & 63;
    const int wave = tid >> 6;    // 0..3
    const int rh   = lane >> 5;   // half-wave id: row of the pair
    const int l32  = lane & 31;
    const int bh    = blockIdx.x >> 2;              // 0..383
    const int qbase = (blockIdx.x & 3) * (TPB * QT);  // 0/96/192/288

    unsigned int* P32 = reinterpret_cast<unsigned int*>(P_lds);

    // ---- prologue: stage ALL of V[bh] into LDS bf16 [d][k], once ----------
    // lane = d (0..63); each lane packs 8 consecutive k for its d.
#pragma unroll
    for (int ii = 0; ii < 12; ++ii) {
        const int kg = ii * 4 + wave;   // k-group (8 k-rows), 0..47
        const float* vp = vmat + ((size_t)bh * S + kg * 8) * D + lane;
        const float v0 = vp[0 * D], v1 = vp[1 * D];
        const float v2 = vp[2 * D], v3 = vp[3 * D];
        const float v4 = vp[4 * D], v5 = vp[5 * D];
        const float v6 = vp[6 * D], v7 = vp[7 * D];
        u32x4 pk;
        pk.x = f2bf(v0) | (f2bf(v1) << 16);
        pk.y = f2bf(v2) | (f2bf(v3) << 16);
        pk.z = f2bf(v4) | (f2bf(v5) << 16);
        pk.w = f2bf(v6) | (f2bf(v7) << 16);
        *reinterpret_cast<u32x4*>(
            &V_lds[lane * VROW + ((kg ^ (lane & 7)) << 3)]) = pk;
    }

    // ---- double-buffered register prefetch of scores+mask (nt) ------------
    f32x4 sv[2][6], mv[2][6];
    auto prefetch = [&](int t, int set) {
        const int q0 = qbase + t * QT;
        const size_t rb = ((size_t)bh * S + q0) * S;
#pragma unroll
        for (int i = 0; i < 2; ++i) {
            const int row = wave * 4 + 2 * i + rh;
            const f32x4* sp =
                reinterpret_cast<const f32x4*>(scores + rb + (size_t)row * S) + l32;
            const f32x4* mp =
                reinterpret_cast<const f32x4*>(dmask  + rb + (size_t)row * S) + l32;
#pragma unroll
            for (int p = 0; p < 3; ++p) {
                sv[set][i * 3 + p] = __builtin_nontemporal_load(sp + 32 * p);
                mv[set][i * 3 + p] = __builtin_nontemporal_load(mp + 32 * p);
            }
        }
    };

    prefetch(0, 0);
    __syncthreads();   // V_lds ready (drains prefetch too; one-time cost)

    const int quad = lane >> 4;
    const int qrow = lane & 15;           // shared 16-row A tile
    const int qx   = qrow & 7;
    const int dcol = wave * 16 + (lane & 15);   // wave owns d-quarter
    const int dx   = dcol & 7;

#pragma unroll
    for (int t = 0; t < TPB; ++t) {
        const int cur = t & 1;
        const int q0  = qbase + t * QT;

        // ---- phase 0: softmax*mask -> bf16 P (unnormalized), from regs ----
#pragma unroll
        for (int i = 0; i < 2; ++i) {
            const int row = wave * 4 + 2 * i + rh;
            const f32x4 s0 = sv[cur][i*3+0], s1 = sv[cur][i*3+1], s2 = sv[cur][i*3+2];
            const f32x4 m0 = mv[cur][i*3+0], m1 = mv[cur][i*3+1], m2 = mv[cur][i*3+2];

            float mx = fmaxf(fmaxf(fmaxf(s0.x, s0.y), fmaxf(s0.z, s0.w)),
                       fmaxf(fmaxf(fmaxf(s1.x, s1.y), fmaxf(s1.z, s1.w)),
                             fmaxf(fmaxf(s2.x, s2.y), fmaxf(s2.z, s2.w))));
#pragma unroll
            for (int d = 16; d >= 1; d >>= 1)   // 32-lane half reduction
                mx = fmaxf(mx, __shfl_xor(mx, d, 64));

            const float e0  = __expf(s0.x - mx), e1  = __expf(s0.y - mx);
            const float e2  = __expf(s0.z - mx), e3  = __expf(s0.w - mx);
            const float e4  = __expf(s1.x - mx), e5  = __expf(s1.y - mx);
            const float e6  = __expf(s1.z - mx), e7  = __expf(s1.w - mx);
            const float e8  = __expf(s2.x - mx), e9  = __expf(s2.y - mx);
            const float e10 = __expf(s2.z - mx), e11 = __expf(s2.w - mx);

            float l = (((e0 + e1) + (e2 + e3)) + ((e4 + e5) + (e6 + e7))) +
                      ((e8 + e9) + (e10 + e11));
#pragma unroll
            for (int d = 16; d >= 1; d >>= 1)
                l += __shfl_xor(l, d, 64);
            if (l32 == 0) linv[row] = 1.0f / l;   // normalization deferred

            u32x2 w0, w1, w2;
            w0.x = f2bf(e0  * m0.x) | (f2bf(e1  * m0.y) << 16);
            w0.y = f2bf(e2  * m0.z) | (f2bf(e3  * m0.w) << 16);
            w1.x = f2bf(e4  * m1.x) | (f2bf(e5  * m1.y) << 16);
            w1.y = f2bf(e6  * m1.z) | (f2bf(e7  * m1.w) << 16);
            w2.x = f2bf(e8  * m2.x) | (f2bf(e9  * m2.y) << 16);
            w2.y = f2bf(e10 * m2.z) | (f2bf(e11 * m2.w) << 16);

            // 16B k-group g; octet-XOR swizzle by (row&7) (R4-proven)
            const int xsw = row & 7;
            const int gb  = l32 >> 1;
            unsigned int* prow =
                P32 + row * (PROW / 2) + ((gb ^ xsw) << 2) + ((l32 & 1) << 1);
            *reinterpret_cast<u32x2*>(prow)       = w0;
            *reinterpret_cast<u32x2*>(prow + 64)  = w1;
            *reinterpret_cast<u32x2*>(prow + 128) = w2;
        }
        __syncthreads();   // P + linv visible to all waves

        // deep prefetch: next tile's 12 KB fly through barrier-free phase 1
        if (t + 1 < TPB) prefetch(t + 1, cur ^ 1);

        // ---- phase 1: 12 MFMA steps, LDS-only, NO barriers ----------------
        f32x4 acc = {};
#pragma unroll
        for (int s = 0; s < 12; ++s) {
            const int kgG = s * 4 + quad;   // global k-group 0..47
            const bf16x8 a = *reinterpret_cast<const bf16x8*>(
                &P_lds[qrow * PROW + ((kgG ^ qx) << 3)]);
            const bf16x8 b = *reinterpret_cast<const bf16x8*>(
                &V_lds[dcol * VROW + ((kgG ^ dx) << 3)]);
            acc = __builtin_amdgcn_mfma_f32_16x16x32_bf16(a, b, acc, 0, 0, 0);
        }

        // ---- epilogue: scale by 1/l, nt-store fp32 ------------------------
        // C/D layout (m89-verified): col = lane&15, row = quad*4 + reg
        const size_t ob   = ((size_t)bh * S + q0) * D;
        const int    orow = quad << 2;
        float iv[4];
#pragma unroll
        for (int r = 0; r < 4; ++r) iv[r] = linv[orow + r];
#pragma unroll
        for (int r = 0; r < 4; ++r) {
            __builtin_nontemporal_store(
                acc[r] * iv[r], out + ob + (size_t)(orow + r) * D + dcol);
        }

        __syncthreads();   // protect P_lds/linv reuse by next tile
    }
}

} // namespace

extern "C" void kernel_launch(void* const* d_in, const int* in_sizes, int n_in,
                              void* d_out, int out_size, void* d_ws, size_t ws_size,
                              hipStream_t stream)
{
    const float* scores = (const float*)d_in[0];  // x429 [B,H,S,S]
    const float* vmat   = (const float*)d_in[1];  // x419 [B,H,S,D]
    const float* dmask  = (const float*)d_in[2];  // dropout_mask [B,H,S,S]
    float* out = (float*)d_out;                   // [B,H,S,D] fp32

    const int BH = 32 * 12;                       // 384
    dim3 grid(BH * 4);                            // 1536 blocks = 6/CU exact
    dim3 block(256);
    softmax_drop_pv<<<grid, block, 0, stream>>>(scores, vmat, dmask, out);
}